// Round 14
// baseline (275.385 us; speedup 1.0000x reference)
//
#include <hip/hip_runtime.h>

#define ANG 9
#define OHW 48
#define IMG 432
#define CIN 64
#define COUT 64
#define ND 9
#define NB 4
#define NVIEW 81
#define NSPAT 2304   // 48*48
#define NTOT 9216    // NB*NSPAT

#define SLABW 81                 // padded gather slab row stride (dwords)
#define SLABSZ (80 * SLABW)      // 6480 floats per var-slab

using f32x4 = __attribute__((ext_vector_type(4))) float;
using s16x8 = __attribute__((ext_vector_type(8))) short;

__device__ __forceinline__ unsigned short f2bf(float f) {
    unsigned u = __float_as_uint(f);
    unsigned r = (u + 0x7FFFu + ((u >> 16) & 1u)) >> 16;   // RNE
    return (unsigned short)r;
}

// ---------------- kernel 1: pack W -> Aw[81][128][64] bf16 -------------------
__global__ void k_wpack(const float* __restrict__ w, unsigned short* __restrict__ aw) {
    int idx = blockIdx.x * 256 + threadIdx.x;
    if (idx >= NVIEW * 128 * 64) return;
    int ci = idx & 63;
    int m  = (idx >> 6) & 127;
    int uv = idx >> 13;
    int u = uv / 9, v = uv % 9;
    int co = m & 63, var = m >> 6;
    int uu = var ? 8 - u : u;
    int vv = var ? 8 - v : v;
    aw[idx] = f2bf(w[((size_t)(co * 64 + ci) * 9 + uu) * 9 + vv]);
}

// ---- compute+store for one h (R13 body): 27 bodies, swapped MFMA, b64 stores
__device__ __forceinline__ void compute_store(const unsigned short* lx,
                                              const s16x8 a0[9],
                                              const unsigned short* __restrict__ abase,
                                              unsigned short* __restrict__ y,
                                              int u, int n0g, int m, int lr, int lh) {
    s16x8 a1n = *reinterpret_cast<const s16x8*>(abase + 32);
#pragma unroll
    for (int v = 0; v < 9; ++v) {
        const int uv = u * 9 + v;
        const s16x8 a1 = a1n;
        if (v < 8)
            a1n = *reinterpret_cast<const s16x8*>(abase + (size_t)(v + 1) * 128 * 64 + 32);
#pragma unroll
        for (int nt = 0; nt < 3; ++nt) {
            const int iw = 9 * (nt * 16 + lr) + v;
            const int g  = (iw >> 2) & 7;
            const s16x8 b0 = *reinterpret_cast<const s16x8*>(&lx[iw * 64 + ((lh ^ g) * 8)]);
            const s16x8 b1 = *reinterpret_cast<const s16x8*>(&lx[iw * 64 + (((4 + lh) ^ g) * 8)]);

            f32x4 acc = (f32x4){0.f, 0.f, 0.f, 0.f};
            acc = __builtin_amdgcn_mfma_f32_16x16x32_bf16(b0, a0[v], acc, 0, 0, 0);
            acc = __builtin_amdgcn_mfma_f32_16x16x32_bf16(b1, a1,    acc, 0, 0, 0);

            const unsigned long long pk =
                  (unsigned long long)f2bf(acc[0])
                | ((unsigned long long)f2bf(acc[1]) << 16)
                | ((unsigned long long)f2bf(acc[2]) << 32)
                | ((unsigned long long)f2bf(acc[3]) << 48);
            *reinterpret_cast<unsigned long long*>(
                &y[((size_t)uv * 128 + m) * NTOT + n0g + nt * 16 + 4 * lh]) = pk;
        }
    }
}

// ---------------- kernel 2: fused pack+GEMM, h-pair, spill-safe prefetch -----
// Block = h-pair: Y bytes per (uv,m,b) row = [192*hp, 192*hp+192) = exactly 3
// full 64B lines -> zero cross-block partial-line write sharing.
// Pipeline: stage h0 | bar | issue f[8] (h1 first-half, 32 VGPR) |
// compute+store h0 (hides HBM latency) | bar | write f[8] + direct-stage
// second half | bar | compute+store h1.
__global__ __launch_bounds__(512, 4)
void k_fused(const float* __restrict__ x,
             const unsigned short* __restrict__ aw,
             unsigned short* __restrict__ y) {
    __shared__ unsigned short lx[IMG * 64];   // 55,296 B, [iw][ci^swz]
    const int L = blockIdx.x;                            // 0..863
    const int logical = (L >> 3) + (L & 7) * 108;        // chunked XCD swizzle
    const int hp = logical % 24;
    const int u  = (logical / 24) % 9;
    const int b  = logical / 216;
    const int h0 = 2 * hp, h1 = 2 * hp + 1;
    const int t = threadIdx.x;
    const int lane = t & 63, wave = t >> 6;
    const int lr = lane & 15;
    const int lh = lane >> 4;
    const int mh = wave >> 2;
    const int mf = wave & 3;
    const int m  = mh * 64 + mf * 16 + lr;
    const int tx = t & 127, ty = t >> 7;

    const unsigned short* abase =
        aw + (((size_t)(u * 9) * 128) + mh * 64 + mf * 16 + lr) * 64 + lh * 8;
    s16x8 a0[9];
#pragma unroll
    for (int v = 0; v < 9; ++v)
        a0[v] = *reinterpret_cast<const s16x8*>(abase + (size_t)v * 128 * 64);

    const float* xp0 = x + (((size_t)b * 64) * IMG + (9 * h0 + u)) * IMG;
    const float* xp1 = x + (((size_t)b * 64) * IMG + (9 * h1 + u)) * IMG;

    // ---- stage h0 (R13 pattern) ----
    if (tx < 108) {
        const float* base = xp0 + 4 * tx;
#pragma unroll 4
        for (int k = 0; k < 16; ++k) {
            const int ci = ty * 16 + k;
            const float4 v4 = *reinterpret_cast<const float4*>(base + (size_t)ci * (IMG * IMG));
            unsigned short us[4] = {f2bf(v4.x), f2bf(v4.y), f2bf(v4.z), f2bf(v4.w)};
#pragma unroll
            for (int jj = 0; jj < 4; ++jj) {
                const int iw = 4 * tx + jj;
                const int sc = ci ^ (((iw >> 2) & 7) << 3);
                lx[iw * 64 + sc] = us[jj];
            }
        }
    }
    __syncthreads();

    // ---- issue first-half h1 prefetch (8 x float4 = 32 VGPR, no spill) ----
    float4 f[8];
    if (tx < 108) {
        const float* base = xp1 + 4 * tx;
#pragma unroll
        for (int k = 0; k < 8; ++k)
            f[k] = *reinterpret_cast<const float4*>(base + (size_t)(ty * 16 + k) * (IMG * IMG));
    }

    // ---- compute+store h0 while h1 first-half loads are in flight ----
    compute_store(lx, a0, abase, y, u, b * NSPAT + h0 * 48, m, lr, lh);
    __syncthreads();

    // ---- h1 staging: write prefetched half, direct-stage second half ----
    if (tx < 108) {
#pragma unroll
        for (int k = 0; k < 8; ++k) {
            const int ci = ty * 16 + k;
            unsigned short us[4] = {f2bf(f[k].x), f2bf(f[k].y), f2bf(f[k].z), f2bf(f[k].w)};
#pragma unroll
            for (int jj = 0; jj < 4; ++jj) {
                const int iw = 4 * tx + jj;
                const int sc = ci ^ (((iw >> 2) & 7) << 3);
                lx[iw * 64 + sc] = us[jj];
            }
        }
        const float* base = xp1 + 4 * tx;
#pragma unroll 4
        for (int k = 8; k < 16; ++k) {
            const int ci = ty * 16 + k;
            const float4 v4 = *reinterpret_cast<const float4*>(base + (size_t)ci * (IMG * IMG));
            unsigned short us[4] = {f2bf(v4.x), f2bf(v4.y), f2bf(v4.z), f2bf(v4.w)};
#pragma unroll
            for (int jj = 0; jj < 4; ++jj) {
                const int iw = 4 * tx + jj;
                const int sc = ci ^ (((iw >> 2) & 7) << 3);
                lx[iw * 64 + sc] = us[jj];
            }
        }
    }
    __syncthreads();

    // ---- compute+store h1 ----
    compute_store(lx, a0, abase, y, u, b * NSPAT + h1 * 48, m, lr, lh);
}

// ---------------- kernel 3: shift-gather-sum over 81 views (gather4, best) ---
__global__ __launch_bounds__(576)
void k_gather4(const unsigned short* __restrict__ y, float* __restrict__ out) {
    __shared__ float lds[2 * SLABSZ];   // 51,840 B
    const int co = blockIdx.x, b = blockIdx.y;
    const int tid = threadIdx.x;

    for (int i = tid; i < 2 * SLABSZ; i += 576) lds[i] = 0.f;

    const int var  = tid / 288;
    const int e0   = (tid % 288) * 8;
    const int srow = e0 / 48, scol = e0 % 48;
    const int ldst = var * SLABSZ + (16 + srow) * SLABW + 16 + scol;
    const unsigned short* ybase =
        y + ((size_t)(var * 64 + co)) * NTOT + (size_t)b * NSPAT + e0;

    const int hh = tid / 12;          // 0..47
    const int w0 = (tid % 12) * 4;    // 0..44
    const int center = (16 + hh) * SLABW + 16 + w0;

    float acc[9][4];
#pragma unroll
    for (int dd = 0; dd < 9; ++dd)
#pragma unroll
        for (int i = 0; i < 4; ++i) acc[dd][i] = 0.f;

    uint4 pre0 = *reinterpret_cast<const uint4*>(ybase);                        // uv=0
    uint4 pre1 = *reinterpret_cast<const uint4*>(ybase + (size_t)128 * NTOT);   // uv=1
    __syncthreads();   // zero-fill done

    for (int uv = 0; uv < NVIEW; ++uv) {
        float4 lo, hi;
        lo.x = __uint_as_float(pre0.x << 16);
        lo.y = __uint_as_float(pre0.x & 0xffff0000u);
        lo.z = __uint_as_float(pre0.y << 16);
        lo.w = __uint_as_float(pre0.y & 0xffff0000u);
        hi.x = __uint_as_float(pre0.z << 16);
        hi.y = __uint_as_float(pre0.z & 0xffff0000u);
        hi.z = __uint_as_float(pre0.w << 16);
        hi.w = __uint_as_float(pre0.w & 0xffff0000u);
        *reinterpret_cast<float4*>(&lds[ldst])     = lo;
        *reinterpret_cast<float4*>(&lds[ldst + 4]) = hi;

        pre0 = pre1;
        if (uv + 2 < NVIEW)
            pre1 = *reinterpret_cast<const uint4*>(ybase + (size_t)(uv + 2) * 128 * NTOT);

        __syncthreads();   // slab complete

        const int uq = uv / 9, vq = uv % 9;
        const int step = (uq - 4) * SLABW + (vq - 4);
        int base = center + 4 * step;                  // dd=0 -> +4*step
#pragma unroll
        for (int dd = 0; dd < 9; ++dd) {
            const float* p = &lds[base + (dd > 4 ? SLABSZ : 0)];
            acc[dd][0] += p[0];
            acc[dd][1] += p[1];
            acc[dd][2] += p[2];
            acc[dd][3] += p[3];
            base -= step;
        }
        __syncthreads();   // reads done before next view's writes
    }

    const size_t ob = (size_t)(b * 64 + co) * 9 * NSPAT + tid * 4;
#pragma unroll
    for (int dd = 0; dd < 9; ++dd) {
        float4 o;
        o.x = acc[dd][0]; o.y = acc[dd][1]; o.z = acc[dd][2]; o.w = acc[dd][3];
        *reinterpret_cast<float4*>(&out[ob + (size_t)dd * NSPAT]) = o;
    }
}

// ---------------- fallback: round-1 direct conv (used if ws too small) -------
__global__ __launch_bounds__(192)
void cost_volume_direct(const float* __restrict__ x,
                        const float* __restrict__ w,
                        float* __restrict__ out) {
    const int ow      = threadIdx.x;
    const int oh      = blockIdx.y * 4 + threadIdx.y;
    const int co_tile = blockIdx.x & 7;
    const int dd      = blockIdx.x >> 3;
    const int b       = blockIdx.z;
    const int d       = dd - 4;
    const int co0     = co_tile * 8;

    int dilat, pad;
    if (d < 0)       { dilat = (-d) * ANG + 1; pad = 36 * (-d); }
    else if (d == 0) { dilat = 1;              pad = 0; }
    else             { dilat = d * ANG - 1;    pad = 36 * d - (ANG - 1); }

    const int ih0 = oh * ANG - pad;
    const int iw0 = ow * ANG - pad;

    float acc[8];
#pragma unroll
    for (int i = 0; i < 8; ++i) acc[i] = 0.f;

    const float* xb = x + (size_t)b * CIN * IMG * IMG;
    for (int kh = 0; kh < ANG; ++kh) {
        const int ih = ih0 + kh * dilat;
        if ((unsigned)ih >= (unsigned)IMG) continue;
        const float* xrow_base = xb + (size_t)ih * IMG;
        const float* wrow      = w + kh * ANG;
        for (int ci = 0; ci < CIN; ++ci) {
            const float* xrow = xrow_base + (size_t)ci * (IMG * IMG);
            float xv[ANG];
#pragma unroll
            for (int kw = 0; kw < ANG; ++kw) {
                const int iw  = iw0 + kw * dilat;
                const bool ok = ((unsigned)iw < (unsigned)IMG);
                const float vv = xrow[ok ? iw : 0];
                xv[kw] = ok ? vv : 0.f;
            }
            const float* wc = wrow + ci * (ANG * ANG);
#pragma unroll
            for (int i = 0; i < 8; ++i) {
                const float* wi = wc + (size_t)(co0 + i) * (CIN * ANG * ANG);
#pragma unroll
                for (int kw = 0; kw < ANG; ++kw)
                    acc[i] = fmaf(xv[kw], wi[kw], acc[i]);
            }
        }
    }
#pragma unroll
    for (int i = 0; i < 8; ++i) {
        const size_t o = ((((size_t)b * COUT + (co0 + i)) * ND + dd) * OHW + oh) * OHW + ow;
        out[o] = acc[i];
    }
}

extern "C" void kernel_launch(void* const* d_in, const int* in_sizes, int n_in,
                              void* d_out, int out_size, void* d_ws, size_t ws_size,
                              hipStream_t stream) {
    const float* x   = (const float*)d_in[0];
    const float* w   = (const float*)d_in[1];
    float*       out = (float*)d_out;

    const size_t AW_BYTES = (size_t)NVIEW * 128 * 64 * 2;        //   1,327,104
    const size_t Y_BYTES  = (size_t)NVIEW * 128 * NTOT * 2;      // 191,102,976
    const size_t NEED     = AW_BYTES + Y_BYTES;                  // ~192.4 MB

    if (ws_size >= NEED) {
        unsigned short* aw = (unsigned short*)d_ws;
        unsigned short* yb = (unsigned short*)((char*)d_ws + AW_BYTES);

        k_wpack  <<<dim3((NVIEW * 128 * 64 + 255) / 256), dim3(256), 0, stream>>>(w, aw);
        k_fused  <<<dim3((OHW / 2) * ANG * NB), dim3(512), 0, stream>>>(x, aw, yb);
        k_gather4<<<dim3(COUT, NB), dim3(576), 0, stream>>>(yb, out);
    } else {
        dim3 grid(8 * ND, OHW / 4, NB);
        dim3 block(OHW, 4, 1);
        cost_volume_direct<<<grid, block, 0, stream>>>(x, w, out);
    }
}

// Round 15
// 206.746 us; speedup vs baseline: 1.3320x; 1.3320x over previous
//
#include <hip/hip_runtime.h>

#define ANG 9
#define OHW 48
#define IMG 432
#define CIN 64
#define COUT 64
#define ND 9
#define NB 4
#define NVIEW 81
#define NSPAT 2304   // 48*48
#define NTOT 9216    // NB*NSPAT

#define SLABW 81                 // padded gather slab row stride (dwords)
#define SLABSZ (80 * SLABW)      // 6480 floats per var-slab

using f32x4 = __attribute__((ext_vector_type(4))) float;
using s16x8 = __attribute__((ext_vector_type(8))) short;

__device__ __forceinline__ unsigned short f2bf(float f) {
    unsigned u = __float_as_uint(f);
    unsigned r = (u + 0x7FFFu + ((u >> 16) & 1u)) >> 16;   // RNE
    return (unsigned short)r;
}

// ---------------- kernel 1: pack W -> Aw[81][128][64] bf16 -------------------
// Aw[uv][co][ci] = W[co][ci][u][v] (var0, d<=0); Aw[uv][64+co][ci] =
// W[co][ci][8-u][8-v] (var1, d>0).
__global__ void k_wpack(const float* __restrict__ w, unsigned short* __restrict__ aw) {
    int idx = blockIdx.x * 256 + threadIdx.x;
    if (idx >= NVIEW * 128 * 64) return;
    int ci = idx & 63;
    int m  = (idx >> 6) & 127;
    int uv = idx >> 13;
    int u = uv / 9, v = uv % 9;
    int co = m & 63, var = m >> 6;
    int uu = var ? 8 - u : u;
    int vv = var ? 8 - v : v;
    aw[idx] = f2bf(w[((size_t)(co * 64 + ci) * 9 + uu) * 9 + vv]);
}

// ---------------- kernel 2: fused pack + per-view GEMM (final anchor) --------
// Measured 148-152 us across R10/R12/R13. Chunked XCD swizzle: h-adjacent
// blocks (which co-write the same Y cache lines) land on the same XCD's L2
// (confirmed: FETCH 132->102 MB). Swapped-operand MFMA -> lane holds m fixed,
// 4 consecutive n -> one packed b64 Y-store per body.
// NOTE for future sessions: remaining ~90 us gap to BW floor is the serial
// stage->barrier->compute structure; reg-prefetch overlap spills under
// launch_bounds(512,4) (R11: f[16], R14: f[8] -- both VGPR 64 + scratch
// traffic). Needs asm-level staging or tr_b16-based LDS layout to break.
__global__ __launch_bounds__(512, 4)
void k_fused(const float* __restrict__ x,
             const unsigned short* __restrict__ aw,
             unsigned short* __restrict__ y) {
    __shared__ unsigned short lx[IMG * 64];   // 55,296 B, [iw][ci^swz]
    const int L = blockIdx.x;                          // 0..1727
    const int logical = (L >> 3) + (L & 7) * 216;      // chunked: 216 tiles/XCD
    const int h = logical % 48;
    const int u = (logical / 48) % 9;
    const int b = logical / 432;
    const int t = threadIdx.x;
    const int ih = 9 * h + u;
    const int lane = t & 63, wave = t >> 6;
    const int lr = lane & 15;
    const int lh = lane >> 4;
    const int mh = wave >> 2;
    const int mf = wave & 3;

    const unsigned short* abase =
        aw + (((size_t)(u * 9) * 128) + mh * 64 + mf * 16 + lr) * 64 + lh * 8;
    s16x8 a0[9];
#pragma unroll
    for (int v = 0; v < 9; ++v)
        a0[v] = *reinterpret_cast<const s16x8*>(abase + (size_t)v * 128 * 64);

    {
        const int tx = t & 127, ty = t >> 7;
        if (tx < 108) {
            const float* base = x + (((size_t)b * 64) * IMG + ih) * IMG + 4 * tx;
#pragma unroll 4
            for (int k = 0; k < 16; ++k) {
                const int ci = ty * 16 + k;
                const float4 v4 = *reinterpret_cast<const float4*>(
                    base + (size_t)ci * (IMG * IMG));
                unsigned short us[4] = {f2bf(v4.x), f2bf(v4.y), f2bf(v4.z), f2bf(v4.w)};
#pragma unroll
                for (int jj = 0; jj < 4; ++jj) {
                    const int iw = 4 * tx + jj;
                    const int sc = ci ^ (((iw >> 2) & 7) << 3);
                    lx[iw * 64 + sc] = us[jj];
                }
            }
        }
    }
    __syncthreads();

    const int m   = mh * 64 + mf * 16 + lr;
    const int n0g = b * NSPAT + h * 48;

    s16x8 a1n = *reinterpret_cast<const s16x8*>(abase + 32);
#pragma unroll
    for (int v = 0; v < 9; ++v) {
        const int uv = u * 9 + v;
        const s16x8 a1 = a1n;
        if (v < 8)
            a1n = *reinterpret_cast<const s16x8*>(abase + (size_t)(v + 1) * 128 * 64 + 32);
#pragma unroll
        for (int nt = 0; nt < 3; ++nt) {
            const int iw = 9 * (nt * 16 + lr) + v;
            const int g  = (iw >> 2) & 7;
            const s16x8 b0 = *reinterpret_cast<const s16x8*>(&lx[iw * 64 + ((lh ^ g) * 8)]);
            const s16x8 b1 = *reinterpret_cast<const s16x8*>(&lx[iw * 64 + (((4 + lh) ^ g) * 8)]);

            // swapped operands: lane holds m = lr (fixed), n = nt*16+4*lh+rr
            f32x4 acc = (f32x4){0.f, 0.f, 0.f, 0.f};
            acc = __builtin_amdgcn_mfma_f32_16x16x32_bf16(b0, a0[v], acc, 0, 0, 0);
            acc = __builtin_amdgcn_mfma_f32_16x16x32_bf16(b1, a1,    acc, 0, 0, 0);

            const unsigned long long pk =
                  (unsigned long long)f2bf(acc[0])
                | ((unsigned long long)f2bf(acc[1]) << 16)
                | ((unsigned long long)f2bf(acc[2]) << 32)
                | ((unsigned long long)f2bf(acc[3]) << 48);
            *reinterpret_cast<unsigned long long*>(
                &y[((size_t)uv * 128 + m) * NTOT + n0g + nt * 16 + 4 * lh]) = pk;
        }
    }
}

// ---------------- kernel 3: shift-gather-sum over 81 views (gather4, final) --
// Single-buffer padded fp32 slabs (2 x 80 x 81), 2 barriers/view, prefetch 2.
// Measured ~53-57 us (R5, R8, R13). Pad-81 breaks the width-80 8-way bank
// conflict. Double-buffer variants regressed twice (R4, R12) -- at 1 block/CU
// the barrier is cheap; bigger LDS + dynamic slab base cost more.
__global__ __launch_bounds__(576)
void k_gather4(const unsigned short* __restrict__ y, float* __restrict__ out) {
    __shared__ float lds[2 * SLABSZ];   // 51,840 B
    const int co = blockIdx.x, b = blockIdx.y;
    const int tid = threadIdx.x;

    for (int i = tid; i < 2 * SLABSZ; i += 576) lds[i] = 0.f;

    const int var  = tid / 288;
    const int e0   = (tid % 288) * 8;
    const int srow = e0 / 48, scol = e0 % 48;
    const int ldst = var * SLABSZ + (16 + srow) * SLABW + 16 + scol;
    const unsigned short* ybase =
        y + ((size_t)(var * 64 + co)) * NTOT + (size_t)b * NSPAT + e0;

    const int hh = tid / 12;          // 0..47
    const int w0 = (tid % 12) * 4;    // 0..44
    const int center = (16 + hh) * SLABW + 16 + w0;

    float acc[9][4];
#pragma unroll
    for (int dd = 0; dd < 9; ++dd)
#pragma unroll
        for (int i = 0; i < 4; ++i) acc[dd][i] = 0.f;

    uint4 pre0 = *reinterpret_cast<const uint4*>(ybase);                        // uv=0
    uint4 pre1 = *reinterpret_cast<const uint4*>(ybase + (size_t)128 * NTOT);   // uv=1
    __syncthreads();   // zero-fill done

    for (int uv = 0; uv < NVIEW; ++uv) {
        float4 lo, hi;
        lo.x = __uint_as_float(pre0.x << 16);
        lo.y = __uint_as_float(pre0.x & 0xffff0000u);
        lo.z = __uint_as_float(pre0.y << 16);
        lo.w = __uint_as_float(pre0.y & 0xffff0000u);
        hi.x = __uint_as_float(pre0.z << 16);
        hi.y = __uint_as_float(pre0.z & 0xffff0000u);
        hi.z = __uint_as_float(pre0.w << 16);
        hi.w = __uint_as_float(pre0.w & 0xffff0000u);
        *reinterpret_cast<float4*>(&lds[ldst])     = lo;
        *reinterpret_cast<float4*>(&lds[ldst + 4]) = hi;

        pre0 = pre1;
        if (uv + 2 < NVIEW)
            pre1 = *reinterpret_cast<const uint4*>(ybase + (size_t)(uv + 2) * 128 * NTOT);

        __syncthreads();   // slab complete

        const int uq = uv / 9, vq = uv % 9;
        const int step = (uq - 4) * SLABW + (vq - 4);
        int base = center + 4 * step;                  // dd=0 -> +4*step
#pragma unroll
        for (int dd = 0; dd < 9; ++dd) {
            const float* p = &lds[base + (dd > 4 ? SLABSZ : 0)];
            acc[dd][0] += p[0];
            acc[dd][1] += p[1];
            acc[dd][2] += p[2];
            acc[dd][3] += p[3];
            base -= step;
        }
        __syncthreads();   // reads done before next view's writes
    }

    const size_t ob = (size_t)(b * 64 + co) * 9 * NSPAT + tid * 4;
#pragma unroll
    for (int dd = 0; dd < 9; ++dd) {
        float4 o;
        o.x = acc[dd][0]; o.y = acc[dd][1]; o.z = acc[dd][2]; o.w = acc[dd][3];
        *reinterpret_cast<float4*>(&out[ob + (size_t)dd * NSPAT]) = o;
    }
}

// ---------------- fallback: round-1 direct conv (used if ws too small) -------
__global__ __launch_bounds__(192)
void cost_volume_direct(const float* __restrict__ x,
                        const float* __restrict__ w,
                        float* __restrict__ out) {
    const int ow      = threadIdx.x;
    const int oh      = blockIdx.y * 4 + threadIdx.y;
    const int co_tile = blockIdx.x & 7;
    const int dd      = blockIdx.x >> 3;
    const int b       = blockIdx.z;
    const int d       = dd - 4;
    const int co0     = co_tile * 8;

    int dilat, pad;
    if (d < 0)       { dilat = (-d) * ANG + 1; pad = 36 * (-d); }
    else if (d == 0) { dilat = 1;              pad = 0; }
    else             { dilat = d * ANG - 1;    pad = 36 * d - (ANG - 1); }

    const int ih0 = oh * ANG - pad;
    const int iw0 = ow * ANG - pad;

    float acc[8];
#pragma unroll
    for (int i = 0; i < 8; ++i) acc[i] = 0.f;

    const float* xb = x + (size_t)b * CIN * IMG * IMG;
    for (int kh = 0; kh < ANG; ++kh) {
        const int ih = ih0 + kh * dilat;
        if ((unsigned)ih >= (unsigned)IMG) continue;
        const float* xrow_base = xb + (size_t)ih * IMG;
        const float* wrow      = w + kh * ANG;
        for (int ci = 0; ci < CIN; ++ci) {
            const float* xrow = xrow_base + (size_t)ci * (IMG * IMG);
            float xv[ANG];
#pragma unroll
            for (int kw = 0; kw < ANG; ++kw) {
                const int iw  = iw0 + kw * dilat;
                const bool ok = ((unsigned)iw < (unsigned)IMG);
                const float vv = xrow[ok ? iw : 0];
                xv[kw] = ok ? vv : 0.f;
            }
            const float* wc = wrow + ci * (ANG * ANG);
#pragma unroll
            for (int i = 0; i < 8; ++i) {
                const float* wi = wc + (size_t)(co0 + i) * (CIN * ANG * ANG);
#pragma unroll
                for (int kw = 0; kw < ANG; ++kw)
                    acc[i] = fmaf(xv[kw], wi[kw], acc[i]);
            }
        }
    }
#pragma unroll
    for (int i = 0; i < 8; ++i) {
        const size_t o = ((((size_t)b * COUT + (co0 + i)) * ND + dd) * OHW + oh) * OHW + ow;
        out[o] = acc[i];
    }
}

extern "C" void kernel_launch(void* const* d_in, const int* in_sizes, int n_in,
                              void* d_out, int out_size, void* d_ws, size_t ws_size,
                              hipStream_t stream) {
    const float* x   = (const float*)d_in[0];
    const float* w   = (const float*)d_in[1];
    float*       out = (float*)d_out;

    const size_t AW_BYTES = (size_t)NVIEW * 128 * 64 * 2;        //   1,327,104
    const size_t Y_BYTES  = (size_t)NVIEW * 128 * NTOT * 2;      // 191,102,976
    const size_t NEED     = AW_BYTES + Y_BYTES;                  // ~192.4 MB

    if (ws_size >= NEED) {
        unsigned short* aw = (unsigned short*)d_ws;
        unsigned short* yb = (unsigned short*)((char*)d_ws + AW_BYTES);

        k_wpack  <<<dim3((NVIEW * 128 * 64 + 255) / 256), dim3(256), 0, stream>>>(w, aw);
        k_fused  <<<dim3(OHW * ANG * NB), dim3(512), 0, stream>>>(x, aw, yb);
        k_gather4<<<dim3(COUT, NB), dim3(576), 0, stream>>>(yb, out);
    } else {
        dim3 grid(8 * ND, OHW / 4, NB);
        dim3 block(OHW, 4, 1);
        cost_volume_direct<<<grid, block, 0, stream>>>(x, w, out);
    }
}